// Round 26
// baseline (28.018 us; speedup 1.0000x reference)
//
#include <hip/hip_runtime.h>

#define IMG    512
#define BAND   4            // output rows per wave
#define NBLK   1024         // 4 waves/block = 2 bands x 2 column-halves
#define NPIX   (16.0 * 512.0 * 512.0)
#define EPS    1e-5f
#define INV81  (1.0f / 81.0f)

// One float4 per image per row: wave covers 256 cols (lane owns 4).
struct Rows { float4 i0, j0; };

__device__ __forceinline__ Rows load_rows(const float* __restrict__ Ib,
                                          const float* __restrict__ Jb,
                                          int y, int col0)
{
    Rows r;
    if (y >= 0 && y < IMG) {          // wave-uniform (y uniform per wave)
        r.i0 = *(const float4*)(Ib + (size_t)y * IMG + col0);
        r.j0 = *(const float4*)(Jb + (size_t)y * IMG + col0);
    } else {
        r.i0 = float4{0.f, 0.f, 0.f, 0.f};
        r.j0 = float4{0.f, 0.f, 0.f, 0.f};
    }
    return r;
}

#define ACC(c, xv, yv)                          \
    sI[c]  += (xv); sJ[c] += (yv);              \
    sII[c]  = fmaf((xv), (xv), sII[c]);         \
    sJJ[c]  = fmaf((yv), (yv), sJJ[c]);         \
    sIJ[c]  = fmaf((xv), (yv), sIJ[c]);

#define UPD(c, nx, ny, ox, oy)                                  \
    sI[c]  += (nx) - (ox);                                      \
    sJ[c]  += (ny) - (oy);                                      \
    sII[c]  = fmaf((nx), (nx), fmaf(-(ox), (ox), sII[c]));      \
    sJJ[c]  = fmaf((ny), (ny), fmaf(-(oy), (oy), sJJ[c]));      \
    sIJ[c]  = fmaf((nx), (ny), fmaf(-(ox), (oy), sIJ[c]));

// NOTE: macro parameter must NOT be named `w` (round-4 lesson).
#define ACC4(R)                                  \
    ACC(0, R.i0.x, R.j0.x) ACC(1, R.i0.y, R.j0.y)\
    ACC(2, R.i0.z, R.j0.z) ACC(3, R.i0.w, R.j0.w)

#define UPD4(NR, OR)                                                      \
    UPD(0, NR.i0.x, NR.j0.x, OR.i0.x, OR.j0.x)                            \
    UPD(1, NR.i0.y, NR.j0.y, OR.i0.y, OR.j0.y)                            \
    UPD(2, NR.i0.z, NR.j0.z, OR.i0.z, OR.j0.z)                            \
    UPD(3, NR.i0.w, NR.j0.w, OR.i0.w, OR.j0.w)

// Horizontal 9-window over 4 column-sums. Proven shuffle pattern (8 shfl,
// consumed immediately). Boundary lanes take an LDS value instead of
// constant 0: at image edges the slot is zero (== zero-pad); at the
// mid-image wave interface it holds the partner wave's edge sums.
__device__ __forceinline__ void hwin4(const float s[4], const float* lSrc,
                                      const float* rSrc, int lane, float w[4])
{
    float l[4], r[4];
    #pragma unroll
    for (int i = 0; i < 4; ++i) {
        float lv = __shfl_up(s[i], 1, 64);
        float rv = __shfl_down(s[i], 1, 64);
        l[i] = (lane == 0)  ? lSrc[i] : lv;
        r[i] = (lane == 63) ? rSrc[i] : rv;
    }
    w[0] = ((l[0] + l[1]) + (l[2] + l[3])) +
           ((s[0] + s[1]) + (s[2] + s[3])) + r[0];
    w[1] = w[0] + r[1] - l[0];
    w[2] = w[1] + r[2] - l[1];
    w[3] = w[2] + r[3] - l[2];
}

// COLUMN-SPLIT RETRY ON THE SAFE TAIL. Round 23 proved the fused RMW tail
// was nondeterministically racy — it was live in rounds 18/20/22, so those
// compute-restructure "failures" were contaminated. This round: r22's
// column-split compute (line-audited 2x: edge routing, barrier parity,
// zero-pad slots all verified) + r24's two-dispatch tail (plain store +
// kernel-boundary coherence; perfect correctness record).
// 4096 waves (2048 bands x 2 halves) = 4 blocks/CU = 4 waves/SIMD — 2x
// TLP on a kernel at ~12% VALUBusy. If absmax fails NOW, the split is
// genuinely buggy -> revert to r24 permanently.
__global__ __launch_bounds__(256) void ncc_band_kernel(
    const float* __restrict__ I, const float* __restrict__ J,
    double* __restrict__ slots)
{
    const int lane  = threadIdx.x & 63;
    const int wid   = threadIdx.x >> 6;
    // bijective XCD swizzle over 1024 blocks (1024 % 8 == 0):
    // XCD k gets 128 contiguous blocks = 2 images (~4MB = its L2).
    const int sblk  = (blockIdx.x & 7) * (NBLK / 8) + (blockIdx.x >> 3);
    const int band  = sblk * 2 + (wid >> 1);      // 0..2047
    const int cside = wid & 1;                    // 0 = cols 0..255, 1 = 256..511
    const int img   = band >> 7;                  // 128 bands / image
    const int y0    = (band & 127) * BAND;
    const int col0  = cside * 256 + lane * 4;

    const float* Ib = I + (size_t)img * IMG * IMG;
    const float* Jb = J + (size_t)img * IMG * IMG;

    // edge column-sum exchange buffers: [buf][wave][5 quantities x 4 cols]
    __shared__ float eL[2][4][20];
    __shared__ float eR[2][4][20];
    if (threadIdx.x < 160) {                      // zero ALL slots once;
        (&eL[0][0][0])[threadIdx.x] = 0.f;        // never-written slots stay
        (&eR[0][0][0])[threadIdx.x] = 0.f;        // 0 == image zero-padding
    }
    __syncthreads();

    float sI[4], sJ[4], sII[4], sJJ[4], sIJ[4];
    #pragma unroll
    for (int c = 0; c < 4; ++c) { sI[c]=0.f; sJ[c]=0.f; sII[c]=0.f; sJJ[c]=0.f; sIJ[c]=0.f; }

    // ---- warm-up rows y0-4..y0+4 (round-19 schedule, halved width):
    //      4 loads in flight up front; od0/od1 held until their UPDs ----
    Rows od0 = load_rows(Ib, Jb, y0 - 4, col0);   // held
    Rows od1 = load_rows(Ib, Jb, y0 - 3, col0);   // held
    Rows A   = load_rows(Ib, Jb, y0 - 2, col0);
    Rows B   = load_rows(Ib, Jb, y0 - 1, col0);

    ACC4(od0)
    ACC4(od1)
    ACC4(A)  A = load_rows(Ib, Jb, y0 + 0, col0);
    ACC4(B)  B = load_rows(Ib, Jb, y0 + 1, col0);
    ACC4(A)  A = load_rows(Ib, Jb, y0 + 2, col0);
    ACC4(B)  B = load_rows(Ib, Jb, y0 + 3, col0);
    ACC4(A)  A = load_rows(Ib, Jb, y0 + 4, col0);
    ACC4(B)  B = load_rows(Ib, Jb, y0 + 5, col0);   // nw0
    ACC4(A)  A = load_rows(Ib, Jb, y0 + 6, col0);   // nw1

    float local = 0.0f;

    // publish this wave's edge sums for the partner half (one lane, 5xb128)
    auto edge_write = [&](int buf) {
        if (cside == 0) {
            if (lane == 63) {                      // right edge -> partner's L
                float* d = &eL[buf][wid + 1][0];
                *(float4*)(d +  0) = float4{sI[0],  sI[1],  sI[2],  sI[3]};
                *(float4*)(d +  4) = float4{sJ[0],  sJ[1],  sJ[2],  sJ[3]};
                *(float4*)(d +  8) = float4{sII[0], sII[1], sII[2], sII[3]};
                *(float4*)(d + 12) = float4{sJJ[0], sJJ[1], sJJ[2], sJJ[3]};
                *(float4*)(d + 16) = float4{sIJ[0], sIJ[1], sIJ[2], sIJ[3]};
            }
        } else {
            if (lane == 0) {                       // left edge -> partner's R
                float* d = &eR[buf][wid - 1][0];
                *(float4*)(d +  0) = float4{sI[0],  sI[1],  sI[2],  sI[3]};
                *(float4*)(d +  4) = float4{sJ[0],  sJ[1],  sJ[2],  sJ[3]};
                *(float4*)(d +  8) = float4{sII[0], sII[1], sII[2], sII[3]};
                *(float4*)(d + 12) = float4{sJJ[0], sJJ[1], sJJ[2], sJJ[3]};
                *(float4*)(d + 16) = float4{sIJ[0], sIJ[1], sIJ[2], sIJ[3]};
            }
        }
    };

    // lean hpass (round-13/19 fold form, t reused for Iv/Jv).
    // buf = DOUBLE-BUFFER PARITY (0/1 only — round-21 lesson).
    auto hpass = [&](int buf) {
        const float* Lb = &eL[buf][wid][0];
        const float* Rb = &eR[buf][wid][0];
        float wI[4], wJ[4], t[4], cross[4];
        hwin4(sI,  Lb + 0,  Rb + 0,  lane, wI);
        hwin4(sJ,  Lb + 4,  Rb + 4,  lane, wJ);
        hwin4(sIJ, Lb + 16, Rb + 16, lane, t);
        #pragma unroll
        for (int k = 0; k < 4; ++k)
            cross[k] = fmaxf(fmaf(-wI[k] * INV81, wJ[k], t[k]), EPS);
        hwin4(sII, Lb + 8,  Rb + 8,  lane, t);
        #pragma unroll
        for (int k = 0; k < 4; ++k)
            wI[k] = fmaxf(fmaf(-wI[k] * INV81, wI[k], t[k]), EPS);   // Iv
        hwin4(sJJ, Lb + 12, Rb + 12, lane, t);
        #pragma unroll
        for (int k = 0; k < 4; ++k)
            wJ[k] = fmaxf(fmaf(-wJ[k] * INV81, wJ[k], t[k]), EPS);   // Jv
        #pragma unroll
        for (int k = 0; k < 4; ++k)
            local += (cross[k] * cross[k]) * __builtin_amdgcn_rcpf(wI[k] * wJ[k]);
    };

    // ---- 4 output rows; exchange edges (double-buffered) before each ----
    edge_write(0); __syncthreads();
    hpass(0);                              // row y0      (reads buf 0)
    UPD4(B, od0)                           // +y0+5, -y0-4 (od0 freed)
    B = load_rows(Ib, Jb, y0 + 7, col0);   // nw2
    edge_write(1); __syncthreads();
    hpass(1);                              // row y0+1    (reads buf 1)
    UPD4(A, od1)                           // +y0+6, -y0-3 (od1 freed)
    A = load_rows(Ib, Jb, y0 - 2, col0);   // od2 re-read (L2-resident)
    edge_write(0); __syncthreads();
    hpass(0);                              // row y0+2    (reads buf 0)
    UPD4(B, A)                             // +y0+7, -y0-2
    edge_write(1); __syncthreads();
    hpass(1);                              // row y0+3    (reads buf 1)

    // ---- wave reduction + intra-block LDS reduce (syncthreads-safe) ----
    #pragma unroll
    for (int off = 32; off > 0; off >>= 1)
        local += __shfl_down(local, off, 64);

    __shared__ float wpart[4];
    if (lane == 0) wpart[wid] = local;
    __syncthreads();
    if (threadIdx.x == 0) {
        double bsum = ((double)wpart[0] + (double)wpart[1]) +
                      ((double)wpart[2] + (double)wpart[3]);
        slots[blockIdx.x] = bsum;          // plain store; kernel boundary
    }                                      // publishes it to dispatch #2
}

__global__ __launch_bounds__(256) void ncc_finalize_kernel(
    const double* __restrict__ slots, float* __restrict__ out)
{
    const int tid = threadIdx.x;
    double2 v0 = *(const double2*)(slots + 2 * tid);         // 0..511
    double2 v1 = *(const double2*)(slots + 512 + 2 * tid);   // 512..1023
    double t = (v0.x + v0.y) + (v1.x + v1.y);
    #pragma unroll
    for (int off = 32; off > 0; off >>= 1)
        t += __shfl_down(t, off, 64);

    __shared__ double wsumd[4];
    if ((tid & 63) == 0) wsumd[tid >> 6] = t;
    __syncthreads();
    if (tid == 0)
        out[0] = (float)(-((wsumd[0] + wsumd[1]) +
                           (wsumd[2] + wsumd[3])) / NPIX);
}

extern "C" void kernel_launch(void* const* d_in, const int* in_sizes, int n_in,
                              void* d_out, int out_size, void* d_ws, size_t ws_size,
                              hipStream_t stream)
{
    const float* I = (const float*)d_in[0];   // y_true
    const float* J = (const float*)d_in[1];   // y_pred
    float* out = (float*)d_out;
    double* slots = (double*)d_ws;            // 1024 doubles, all written each call

    ncc_band_kernel<<<NBLK, 256, 0, stream>>>(I, J, slots);
    ncc_finalize_kernel<<<1, 256, 0, stream>>>(slots, out);
}